// Round 13
// baseline (246.322 us; speedup 1.0000x reference)
//
#include <hip/hip_runtime.h>
#include <math.h>

// Problem constants
#define BATCH 512
#define M 128
#define D 512
#define PITER 9           // power iterations (L inflated 1.15x; converged lam is step-independent)
#define NRUN 58           // FISTA iterations (rate ~0.69 -> 0.69^58 ~ 4e-10; reference runs 400)
#define KC 64             // k-columns per staging chunk
#define NCH (D / KC)      // 8 chunks
#define SSTR 72           // staging row stride in halfs (144 B): 16B-aligned, even bank-quad spread
#define GSH 136           // G fp16 LDS row stride in halfs (272 B): 16B-aligned rows, 2-way banks
#define SCL 0.0009765625f // 2^-10 per-iteration power scaling

typedef __attribute__((ext_vector_type(8))) _Float16 h8;
typedef __attribute__((ext_vector_type(2))) _Float16 h2;
typedef __attribute__((ext_vector_type(4))) float f4;
typedef __attribute__((ext_vector_type(2))) float v2f;

// ===== fused; build = 4-wave MFMA, solve = ONE wave, pure-VALU, zero-LDS loop =====
// r13: MFMA removed from the solve. r10/r11/r12 all neutral at ~2120 cyc/iter ->
// consistent with per-wave MFMA issue-block (~60 cyc x 32 MFMA, §8 "MFMA blocks
// its wave"); a solo wave cannot hide its own MFMA latency. New solve iteration:
// 64 v_readlane (packed y-pair broadcast) + 128 v_dot2_f32_f16 + ~15 VALU
// (~450 cyc/iter, 4.7x) with NO LDS, NO waitcnt, NO barrier -- register-only.
// Lane l owns rows {2l,2l+1}; G as packed-h2 regs g0[64]/g1[64] (128 VGPR).
__launch_bounds__(256, 2)
__global__ void fused_kernel(const float* __restrict__ pred,
                             const float* __restrict__ ctr,
                             float* __restrict__ out)
{
    // union{ fp16 staging 2x18432 B , fp16 G 128xGSH = 34816 B }
    __shared__ __align__(16) char uni[2 * M * SSTR * 2];   // 36864 B
    __shared__ __align__(16) float p_s[D];
    __shared__ float mask_s[M];
    __shared__ float b_s[M];
    __shared__ float wredA[4];

    _Float16* hiS = (_Float16*)uni;                        // [2][M*SSTR] during build
    _Float16* g16 = (_Float16*)uni;                        // [M][GSH] after build

    const int tid = threadIdx.x;
    const int blk = blockIdx.x;
    const int w = tid >> 6, l = tid & 63;                  // wave, lane
    const int row = tid >> 1;                              // staging row (0..127)
    const int sg = tid & 1;                                // 32-col half of the 64-col chunk
    const int fm = l & 15;                                 // MFMA fragment row/col
    const int fq = l >> 4;                                 // MFMA k-quad

    const float* predRow = pred + (size_t)blk * D;
    const float* ctrBase = ctr + (size_t)blk * (size_t)(M * D);

    // ---- stage p (2 elems/thread), ||p||^2 -> all threads ----
    float pv0 = predRow[tid];
    float pv1 = predRow[tid + 256];
    p_s[tid] = pv0;
    p_s[tid + 256] = pv1;
    float v = pv0 * pv0 + pv1 * pv1;
    #pragma unroll
    for (int off = 32; off > 0; off >>= 1) v += __shfl_xor(v, off, 64);
    if (l == 0) wredA[w] = v;
    __syncthreads();
    const float pn2 = wredA[0] + wredA[1] + wredA[2] + wredA[3];

    // ---- build: G = (masked C_fp16)(masked C_fp16)^T via MFMA, depth-2 prefetch ----
    f4 acc[2][8];
    #pragma unroll
    for (int i = 0; i < 2; ++i)
        #pragma unroll
        for (int jx = 0; jx < 8; ++jx)
            acc[i][jx] = (f4)0.0f;

    float rs = 0.0f, bp = 0.0f;
    const float* src = ctrBase + (size_t)row * D + 32 * sg;  // this thread's 32-col strip base
    f4 buf[3][8];                                            // 3-deep rotation (static idx via full unroll)
    #pragma unroll
    for (int j = 0; j < 8; ++j) buf[0][j] = *(const f4*)(src + 4 * j);
    #pragma unroll
    for (int j = 0; j < 8; ++j) buf[1][j] = *(const f4*)(src + 64 + 4 * j);

    #pragma unroll
    for (int kc = 0; kc < NCH; ++kc) {
        const int cb = kc % 3;
        _Float16* hc = hiS + (kc & 1) * (M * SSTR);
        // convert + stage 32 halfs
        #pragma unroll
        for (int j = 0; j < 4; ++j) {
            f4 x = buf[cb][2 * j], y = buf[cb][2 * j + 1];
            h8 hv = {(_Float16)x.x, (_Float16)x.y, (_Float16)x.z, (_Float16)x.w,
                     (_Float16)y.x, (_Float16)y.y, (_Float16)y.z, (_Float16)y.w};
            *(h8*)(hc + row * SSTR + 32 * sg + 8 * j) = hv;
        }
        // row-abs-sum and b-dot
        #pragma unroll
        for (int j = 0; j < 8; ++j) {
            f4 x = buf[cb][j];
            rs += fabsf(x.x) + fabsf(x.y) + fabsf(x.z) + fabsf(x.w);
            f4 pp = *(const f4*)(p_s + 64 * kc + 32 * sg + 4 * j);
            bp += x.x * pp.x + x.y * pp.y + x.z * pp.z + x.w * pp.w;
        }
        // issue chunk kc+2 loads BEFORE the barrier
        if (kc + 2 < NCH) {
            const int nb = (kc + 2) % 3;
            #pragma unroll
            for (int j = 0; j < 8; ++j) buf[nb][j] = *(const f4*)(src + 64 * (kc + 2) + 4 * j);
        }
        __syncthreads();   // staged data visible; dbuf -> 1 barrier/chunk
        // MFMA: rows [32w,32w+32) x all 128 cols
        #pragma unroll
        for (int ks = 0; ks < 2; ++ks) {
            h8 Ah[2];
            #pragma unroll
            for (int t = 0; t < 2; ++t)
                Ah[t] = *(const h8*)(hc + (32 * w + 16 * t + fm) * SSTR + 32 * ks + 8 * fq);
            #pragma unroll
            for (int tc = 0; tc < 8; ++tc) {
                h8 Bh = *(const h8*)(hc + (16 * tc + fm) * SSTR + 32 * ks + 8 * fq);
                acc[0][tc] = __builtin_amdgcn_mfma_f32_16x16x32_f16(Ah[0], Bh, acc[0][tc], 0, 0, 0);
                acc[1][tc] = __builtin_amdgcn_mfma_f32_16x16x32_f16(Ah[1], Bh, acc[1][tc], 0, 0, 0);
            }
        }
    }

    // ---- row mask + b (pairwise xor over the 2 col-halves) ----
    rs += __shfl_xor(rs, 1, 64);
    bp += __shfl_xor(bp, 1, 64);
    const bool okr = rs > 1e-7f;
    if (sg == 0) {
        mask_s[row] = okr ? 1.0f : 0.0f;
        b_s[row] = okr ? -bp : 0.0f;      // b = C_masked * (-pred)
    }
    __syncthreads();   // mask/b ready; hiS dead -> g16 may overwrite

    // hoist masks (C/D layout: col=lane&15, row=(lane>>4)*4+reg)
    float mc[8], mr[2][4];
    #pragma unroll
    for (int tc = 0; tc < 8; ++tc) mc[tc] = mask_s[16 * tc + fm];
    #pragma unroll
    for (int t = 0; t < 2; ++t)
        #pragma unroll
        for (int r = 0; r < 4; ++r) mr[t][r] = mask_s[32 * w + 16 * t + 4 * fq + r];

    // ---- masked G -> fp16 LDS, full 128x128, single barrier ----
    #pragma unroll
    for (int t = 0; t < 2; ++t)
        #pragma unroll
        for (int r = 0; r < 4; ++r) {
            const int grow = 32 * w + 16 * t + 4 * fq + r;
            const float mrr = mr[t][r];
            #pragma unroll
            for (int tc = 0; tc < 8; ++tc)
                g16[grow * GSH + 16 * tc + fm] = (_Float16)(acc[t][tc][r] * mrr * mc[tc]);
        }
    __syncthreads();

    // solver wave: 0 or 2 by block index. NOW LOAD-BEARING: the solve is
    // VALU-issue-bound, so co-resident blocks' solvers MUST be on different SIMDs.
    const int sv = (((blk >> 8) ^ blk) & 1) << 1;
    if (w != sv) return;    // other waves done; loop below is register-only

    // ---- solo solve: lane l owns rows {2l, 2l+1}; G as packed h2 regs ----
    h2 g0[64], g1[64];      // g0[kk] = G[2l][2kk..2kk+1], g1[kk] = G[2l+1][...]
    #pragma unroll
    for (int c8 = 0; c8 < 16; ++c8) {
        h8 r0 = *(const h8*)(g16 + (2 * l) * GSH + 8 * c8);
        h8 r1 = *(const h8*)(g16 + (2 * l + 1) * GSH + 8 * c8);
        f4 p0 = __builtin_bit_cast(f4, r0); asm volatile("" : "+v"(p0));
        r0 = __builtin_bit_cast(h8, p0);
        f4 p1 = __builtin_bit_cast(f4, r1); asm volatile("" : "+v"(p1));
        r1 = __builtin_bit_cast(h8, p1);
        #pragma unroll
        for (int j = 0; j < 4; ++j) {
            g0[4 * c8 + j] = h2{r0[2 * j], r0[2 * j + 1]};
            g1[4 * c8 + j] = h2{r1[2 * j], r1[2 * j + 1]};
        }
    }
    const v2f b2 = v2f{b_s[2 * l], b_s[2 * l + 1]};

    // u = G y: 64 packed readlane broadcasts + 128 fdot2, 8 accum chains
    auto matvec = [&](unsigned ypk) -> v2f {
        float a0 = 0.f, a1 = 0.f, a2 = 0.f, a3 = 0.f;
        float c0 = 0.f, c1 = 0.f, c2 = 0.f, c3 = 0.f;
        #pragma unroll
        for (int kk = 0; kk < 64; ++kk) {
            const int s = __builtin_amdgcn_readlane((int)ypk, kk);  // {y[2kk],y[2kk+1]}
            const h2 ys = __builtin_bit_cast(h2, s);
            switch (kk & 3) {
                case 0: a0 = __builtin_amdgcn_fdot2(g0[kk], ys, a0, false);
                        c0 = __builtin_amdgcn_fdot2(g1[kk], ys, c0, false); break;
                case 1: a1 = __builtin_amdgcn_fdot2(g0[kk], ys, a1, false);
                        c1 = __builtin_amdgcn_fdot2(g1[kk], ys, c1, false); break;
                case 2: a2 = __builtin_amdgcn_fdot2(g0[kk], ys, a2, false);
                        c2 = __builtin_amdgcn_fdot2(g1[kk], ys, c2, false); break;
                default: a3 = __builtin_amdgcn_fdot2(g0[kk], ys, a3, false);
                         c3 = __builtin_amdgcn_fdot2(g1[kk], ys, c3, false); break;
            }
        }
        return v2f{(a0 + a1) + (a2 + a3), (c0 + c1) + (c2 + c3)};
    };
    auto packy = [&](float x, float y) -> unsigned {
        h2 t = h2{(_Float16)x, (_Float16)y};
        return __builtin_bit_cast(unsigned, t);
    };
    auto wsum = [&](float x) {
        #pragma unroll
        for (int off = 1; off < 64; off <<= 1) x += __shfl_xor(x, off, 64);
        return x;
    };

    // ---- power iteration (unnormalized, 2^-10 per-step scaling) ----
    unsigned ypk = packy(1.0f, 1.0f);
    v2f v2 = v2f{1.0f, 1.0f};
    for (int it = 0; it < PITER; ++it) {
        v2f u = matvec(ypk);
        v2.x = u.x * SCL; v2.y = u.y * SCL;
        ypk = packy(v2.x, v2.y);
    }
    float step;
    {
        v2f u = matvec(ypk);               // u = G v (raw)
        const float nv = wsum(v2.x * v2.x + v2.y * v2.y);
        const float nu = wsum(u.x * u.x + u.y * u.y);
        const float L = sqrtf(nu / fmaxf(nv, 1e-30f));
        step = 1.0f / fmaxf(1.15f * L, 1e-12f);
    }
    const v2f sb = v2f{step * b2.x, step * b2.y};

    // ---- FISTA: rows {2l, 2l+1}; register-only iteration ----
    v2f lam = v2f{0.0f, 0.0f}, yv = v2f{0.0f, 0.0f};
    float tk = 1.0f;
    ypk = packy(0.0f, 0.0f);
    for (int it = 0; it < NRUN; ++it) {
        v2f u = matvec(ypk);               // u = G y (raw)
        const float tkn = 0.5f * (1.0f + sqrtf(1.0f + 4.0f * tk * tk));
        const float bet = (tk - 1.0f) / tkn;
        v2f ln;
        ln.x = fmaxf(yv.x - step * u.x + sb.x, 0.0f);
        ln.y = fmaxf(yv.y - step * u.y + sb.y, 0.0f);
        yv.x = ln.x + bet * (ln.x - lam.x);
        yv.y = ln.y + bet * (ln.y - lam.y);
        lam = ln; tk = tkn;
        ypk = packy(yv.x, yv.y);
    }

    // ---- cosine via lam^T b, lam^T G lam, ||p|| ----
    {
        ypk = packy(lam.x, lam.y);         // lam through fp16, as before
        v2f u = matvec(ypk);               // u = G lam (raw)
        const float sg_ = wsum(lam.x * u.x + lam.y * u.y);
        const float sb_ = wsum(lam.x * b2.x + lam.y * b2.y);
        if (l == 0) {
            const float glg = sg_;                  // lam^T G lam
            const float np_ = sqrtf(fmaxf(glg, 0.0f));
            const float pdot = sb_ / (np_ + 1e-12f);
            const float qn = fmaxf(np_ / (np_ + 1e-12f), 1e-8f);
            const float pn = fmaxf(sqrtf(pn2), 1e-8f);
            const float c_ = pdot / (pn * qn);
            atomicAdd(out, -c_ * (1.0f / (float)BATCH));
        }
    }
}

extern "C" void kernel_launch(void* const* d_in, const int* in_sizes, int n_in,
                              void* d_out, int out_size, void* d_ws, size_t ws_size,
                              hipStream_t stream) {
    const float* pred = (const float*)d_in[0];  // (512, 512)
    const float* ctr  = (const float*)d_in[1];  // (512, 128, 512)
    float* out = (float*)d_out;

    (void)d_ws; (void)ws_size;                  // G never leaves the CU
    hipMemsetAsync(d_out, 0, out_size, stream); // capture-safe memset node (out accumulated via atomicAdd)
    fused_kernel<<<BATCH, 256, 0, stream>>>(pred, ctr, out);
}

// Round 14
// 220.905 us; speedup vs baseline: 1.1151x; 1.1151x over previous
//
#include <hip/hip_runtime.h>
#include <math.h>

// Problem constants
#define BATCH 512
#define M 128
#define D 512
#define PITER 9           // power iterations (L inflated 1.15x; converged lam is step-independent)
#define NRUN 40           // FISTA iterations (rate ~0.69 -> 0.69^40 ~ 4e-7; cosine error is
                          // second-order in lam error (~1e-13) -- far below the fp16-G bias we
                          // already pass with. r14: 58->40 is BOTH a win and a per-iter-cost
                          // measurement: delta_us/18iters*2.4GHz = cyc/iter of the solve.
#define KC 64             // k-columns per staging chunk
#define NCH (D / KC)      // 8 chunks
#define SSTR 72           // staging row stride in halfs (144 B): 16B-aligned, even bank-quad spread
#define GSH 136           // G fp16 LDS row stride in halfs (272 B): 16B-aligned rows, 2-way banks
#define SCL 0.0009765625f // 2^-10 per-iteration power scaling

typedef __attribute__((ext_vector_type(8))) _Float16 h8;
typedef __attribute__((ext_vector_type(4))) float f4;

// ===== fused; build = 4-wave MFMA, solve = ONE wave MFMA, barrier-free (r11 base) =====
// r13's pure-VALU solve REGRESSED (110 vs 91.5): 1-wave MFMA matvec is the best
// measured engine. This round: revert to r11, cut NRUN only (single variable).
__launch_bounds__(256, 2)
__global__ void fused_kernel(const float* __restrict__ pred,
                             const float* __restrict__ ctr,
                             float* __restrict__ out)
{
    // union{ fp16 staging 2x18432 B , fp16 G 128xGSH = 34816 B }
    __shared__ __align__(16) char uni[2 * M * SSTR * 2];   // 36864 B
    __shared__ __align__(16) float p_s[D];
    __shared__ __align__(16) _Float16 yh[M];               // y broadcast vector (fp16)
    __shared__ float mask_s[M];
    __shared__ float b_s[M];
    __shared__ float wredA[4];

    _Float16* hiS = (_Float16*)uni;                        // [2][M*SSTR] during build
    _Float16* g16 = (_Float16*)uni;                        // [M][GSH] after build

    const int tid = threadIdx.x;
    const int blk = blockIdx.x;
    const int w = tid >> 6, l = tid & 63;                  // wave, lane
    const int row = tid >> 1;                              // staging row (0..127)
    const int sg = tid & 1;                                // 32-col half of the 64-col chunk
    const int fm = l & 15;                                 // MFMA fragment row/col
    const int fq = l >> 4;                                 // MFMA k-quad

    const float* predRow = pred + (size_t)blk * D;
    const float* ctrBase = ctr + (size_t)blk * (size_t)(M * D);

    // ---- stage p (2 elems/thread), ||p||^2 -> all threads (solver wave varies) ----
    float pv0 = predRow[tid];
    float pv1 = predRow[tid + 256];
    p_s[tid] = pv0;
    p_s[tid + 256] = pv1;
    float v = pv0 * pv0 + pv1 * pv1;
    #pragma unroll
    for (int off = 32; off > 0; off >>= 1) v += __shfl_xor(v, off, 64);
    if (l == 0) wredA[w] = v;
    __syncthreads();
    const float pn2 = wredA[0] + wredA[1] + wredA[2] + wredA[3];

    // ---- build: G = (masked C_fp16)(masked C_fp16)^T via MFMA, depth-2 prefetch ----
    f4 acc[2][8];
    #pragma unroll
    for (int i = 0; i < 2; ++i)
        #pragma unroll
        for (int jx = 0; jx < 8; ++jx)
            acc[i][jx] = (f4)0.0f;

    float rs = 0.0f, bp = 0.0f;
    const float* src = ctrBase + (size_t)row * D + 32 * sg;  // this thread's 32-col strip base
    f4 buf[3][8];                                            // 3-deep rotation (static idx via full unroll)
    #pragma unroll
    for (int j = 0; j < 8; ++j) buf[0][j] = *(const f4*)(src + 4 * j);
    #pragma unroll
    for (int j = 0; j < 8; ++j) buf[1][j] = *(const f4*)(src + 64 + 4 * j);

    #pragma unroll
    for (int kc = 0; kc < NCH; ++kc) {
        const int cb = kc % 3;
        _Float16* hc = hiS + (kc & 1) * (M * SSTR);
        // convert + stage 32 halfs
        #pragma unroll
        for (int j = 0; j < 4; ++j) {
            f4 x = buf[cb][2 * j], y = buf[cb][2 * j + 1];
            h8 hv = {(_Float16)x.x, (_Float16)x.y, (_Float16)x.z, (_Float16)x.w,
                     (_Float16)y.x, (_Float16)y.y, (_Float16)y.z, (_Float16)y.w};
            *(h8*)(hc + row * SSTR + 32 * sg + 8 * j) = hv;
        }
        // row-abs-sum and b-dot
        #pragma unroll
        for (int j = 0; j < 8; ++j) {
            f4 x = buf[cb][j];
            rs += fabsf(x.x) + fabsf(x.y) + fabsf(x.z) + fabsf(x.w);
            f4 pp = *(const f4*)(p_s + 64 * kc + 32 * sg + 4 * j);
            bp += x.x * pp.x + x.y * pp.y + x.z * pp.z + x.w * pp.w;
        }
        // issue chunk kc+2 loads BEFORE the barrier
        if (kc + 2 < NCH) {
            const int nb = (kc + 2) % 3;
            #pragma unroll
            for (int j = 0; j < 8; ++j) buf[nb][j] = *(const f4*)(src + 64 * (kc + 2) + 4 * j);
        }
        __syncthreads();   // staged data visible; dbuf -> 1 barrier/chunk
        // MFMA: rows [32w,32w+32) x all 128 cols
        #pragma unroll
        for (int ks = 0; ks < 2; ++ks) {
            h8 Ah[2];
            #pragma unroll
            for (int t = 0; t < 2; ++t)
                Ah[t] = *(const h8*)(hc + (32 * w + 16 * t + fm) * SSTR + 32 * ks + 8 * fq);
            #pragma unroll
            for (int tc = 0; tc < 8; ++tc) {
                h8 Bh = *(const h8*)(hc + (16 * tc + fm) * SSTR + 32 * ks + 8 * fq);
                acc[0][tc] = __builtin_amdgcn_mfma_f32_16x16x32_f16(Ah[0], Bh, acc[0][tc], 0, 0, 0);
                acc[1][tc] = __builtin_amdgcn_mfma_f32_16x16x32_f16(Ah[1], Bh, acc[1][tc], 0, 0, 0);
            }
        }
    }

    // ---- row mask + b (pairwise xor over the 2 col-halves) ----
    rs += __shfl_xor(rs, 1, 64);
    bp += __shfl_xor(bp, 1, 64);
    const bool okr = rs > 1e-7f;
    if (sg == 0) {
        mask_s[row] = okr ? 1.0f : 0.0f;
        b_s[row] = okr ? -bp : 0.0f;      // b = C_masked * (-pred)
    }
    if (tid < M) yh[tid] = (_Float16)1.0f;   // power-iteration v0 = ones
    __syncthreads();   // mask/b/y0 ready; hiS dead -> g16 may overwrite

    // hoist masks (C/D layout: col=lane&15, row=(lane>>4)*4+reg)
    float mc[8], mr[2][4];
    #pragma unroll
    for (int tc = 0; tc < 8; ++tc) mc[tc] = mask_s[16 * tc + fm];
    #pragma unroll
    for (int t = 0; t < 2; ++t)
        #pragma unroll
        for (int r = 0; r < 4; ++r) mr[t][r] = mask_s[32 * w + 16 * t + 4 * fq + r];

    // ---- masked G -> fp16 LDS, full 128x128, single barrier ----
    #pragma unroll
    for (int t = 0; t < 2; ++t)
        #pragma unroll
        for (int r = 0; r < 4; ++r) {
            const int grow = 32 * w + 16 * t + 4 * fq + r;
            const float mrr = mr[t][r];
            #pragma unroll
            for (int tc = 0; tc < 8; ++tc)
                g16[grow * GSH + 16 * tc + fm] = (_Float16)(acc[t][tc][r] * mrr * mc[tc]);
        }
    __syncthreads();

    // solver wave: 0 or 2 by block index, so co-resident blocks' solvers land on
    // different SIMDs
    const int sv = (((blk >> 8) ^ blk) & 1) << 1;
    if (w != sv) return;    // other waves done; no barriers below (wave-internal only)

    // ---- solo solve on wave sv ----
    // B-frags of G (symmetric): gb[t][kt] = G[16t+fm][32kt+8fq .. +8)
    h8 gb[8][4];
    #pragma unroll
    for (int t = 0; t < 8; ++t)
        #pragma unroll
        for (int kt = 0; kt < 4; ++kt)
            gb[t][kt] = *(const h8*)(g16 + (16 * t + fm) * GSH + 32 * kt + 8 * fq);

    float b8[8];
    #pragma unroll
    for (int t = 0; t < 8; ++t) b8[t] = b_s[16 * t + fm];

    h8 ya[4];
    // fence + load ya: one LDS drain per iteration; sched_barrier per rule #18
    auto load_ya = [&]() {
        asm volatile("s_waitcnt lgkmcnt(0)" ::: "memory");
        __builtin_amdgcn_sched_barrier(0);
        #pragma unroll
        for (int kt = 0; kt < 4; ++kt) ya[kt] = *(const h8*)(yh + 32 * kt + 8 * fq);
    };
    auto wsum = [&](float x) {
        #pragma unroll
        for (int off = 1; off < 64; off <<= 1) x += __shfl_xor(x, off, 64);
        return x;
    };

    // ---- power iteration (unnormalized, 2^-10 per-step scaling) ----
    float v8[8];
    #pragma unroll
    for (int t = 0; t < 8; ++t) v8[t] = 1.0f;
    for (int it = 0; it < PITER; ++it) {
        load_ya();
        #pragma unroll
        for (int tq = 0; tq < 2; ++tq) {
            f4 c[4];
            #pragma unroll
            for (int j = 0; j < 4; ++j) c[j] = (f4)0.0f;
            #pragma unroll
            for (int kt = 0; kt < 4; ++kt)
                #pragma unroll
                for (int j = 0; j < 4; ++j)
                    c[j] = __builtin_amdgcn_mfma_f32_16x16x32_f16(ya[kt], gb[4 * tq + j][kt], c[j], 0, 0, 0);
            #pragma unroll
            for (int j = 0; j < 4; ++j) v8[4 * tq + j] = c[j][0] * SCL;
            if (l < 16) {
                #pragma unroll
                for (int j = 0; j < 4; ++j) yh[16 * (4 * tq + j) + l] = (_Float16)v8[4 * tq + j];
            }
        }
    }
    float u8[8];
    float step;
    {
        load_ya();                         // u = G v (raw)
        f4 c[8];
        #pragma unroll
        for (int t = 0; t < 8; ++t) c[t] = (f4)0.0f;
        #pragma unroll
        for (int kt = 0; kt < 4; ++kt)
            #pragma unroll
            for (int t = 0; t < 8; ++t)
                c[t] = __builtin_amdgcn_mfma_f32_16x16x32_f16(ya[kt], gb[t][kt], c[t], 0, 0, 0);
        #pragma unroll
        for (int t = 0; t < 8; ++t) u8[t] = c[t][0];
        float xv = 0.0f, xu = 0.0f;
        if (l < 16) {                      // rows counted once (fq==0 lanes)
            #pragma unroll
            for (int t = 0; t < 8; ++t) { xv += v8[t] * v8[t]; xu += u8[t] * u8[t]; }
        }
        const float nv = wsum(xv);
        const float nu = wsum(xu);
        const float L = sqrtf(nu / fmaxf(nv, 1e-30f));
        step = 1.0f / fmaxf(1.15f * L, 1e-12f);
    }
    float sb8[8];
    #pragma unroll
    for (int t = 0; t < 8; ++t) sb8[t] = step * b8[t];

    // ---- FISTA: rows {16t+fm} per lane; per-quad update+publish under next quad's MFMAs ----
    if (l < 16) {
        #pragma unroll
        for (int t = 0; t < 8; ++t) yh[16 * t + l] = (_Float16)0.0f;   // y0 = 0
    }
    float lam8[8], yv8[8];
    #pragma unroll
    for (int t = 0; t < 8; ++t) { lam8[t] = 0.0f; yv8[t] = 0.0f; }
    float tk = 1.0f;
    for (int it = 0; it < NRUN; ++it) {
        load_ya();
        const float tkn = 0.5f * (1.0f + sqrtf(1.0f + 4.0f * tk * tk));
        const float bet = (tk - 1.0f) / tkn;
        #pragma unroll
        for (int tq = 0; tq < 2; ++tq) {
            f4 c[4];
            #pragma unroll
            for (int j = 0; j < 4; ++j) c[j] = (f4)0.0f;
            #pragma unroll
            for (int kt = 0; kt < 4; ++kt)
                #pragma unroll
                for (int j = 0; j < 4; ++j)
                    c[j] = __builtin_amdgcn_mfma_f32_16x16x32_f16(ya[kt], gb[4 * tq + j][kt], c[j], 0, 0, 0);
            #pragma unroll
            for (int j = 0; j < 4; ++j) {
                const int t = 4 * tq + j;
                const float ln = fmaxf(yv8[t] - step * c[j][0] + sb8[t], 0.0f);
                yv8[t] = ln + bet * (ln - lam8[t]);
                lam8[t] = ln;
            }
            if (l < 16) {
                #pragma unroll
                for (int j = 0; j < 4; ++j) yh[16 * (4 * tq + j) + l] = (_Float16)yv8[4 * tq + j];
            }
        }
        tk = tkn;
    }

    // ---- cosine via lam^T b, lam^T G lam, ||p|| ----
    if (l < 16) {
        #pragma unroll
        for (int t = 0; t < 8; ++t) yh[16 * t + l] = (_Float16)lam8[t];
    }
    {
        load_ya();                         // u = G lam (raw)
        f4 c[8];
        #pragma unroll
        for (int t = 0; t < 8; ++t) c[t] = (f4)0.0f;
        #pragma unroll
        for (int kt = 0; kt < 4; ++kt)
            #pragma unroll
            for (int t = 0; t < 8; ++t)
                c[t] = __builtin_amdgcn_mfma_f32_16x16x32_f16(ya[kt], gb[t][kt], c[t], 0, 0, 0);
        float xg = 0.0f, xb = 0.0f;
        if (l < 16) {
            #pragma unroll
            for (int t = 0; t < 8; ++t) { xg += lam8[t] * c[t][0]; xb += lam8[t] * b8[t]; }
        }
        const float sg_ = wsum(xg);
        const float sb_ = wsum(xb);
        if (l == 0) {
            const float glg = sg_;                  // lam^T G lam
            const float np_ = sqrtf(fmaxf(glg, 0.0f));
            const float pdot = sb_ / (np_ + 1e-12f);
            const float qn = fmaxf(np_ / (np_ + 1e-12f), 1e-8f);
            const float pn = fmaxf(sqrtf(pn2), 1e-8f);
            const float c_ = pdot / (pn * qn);
            atomicAdd(out, -c_ * (1.0f / (float)BATCH));
        }
    }
}

extern "C" void kernel_launch(void* const* d_in, const int* in_sizes, int n_in,
                              void* d_out, int out_size, void* d_ws, size_t ws_size,
                              hipStream_t stream) {
    const float* pred = (const float*)d_in[0];  // (512, 512)
    const float* ctr  = (const float*)d_in[1];  // (512, 128, 512)
    float* out = (float*)d_out;

    (void)d_ws; (void)ws_size;                  // G never leaves the CU
    hipMemsetAsync(d_out, 0, out_size, stream); // capture-safe memset node (out accumulated via atomicAdd)
    fused_kernel<<<BATCH, 256, 0, stream>>>(pred, ctr, out);
}